// Round 2
// 118.857 us; speedup vs baseline: 1.0302x; 1.0302x over previous
//
#include <hip/hip_runtime.h>

// B=64, K=8, H=W=128 (HW=16384). float32 in/out.
// out[0] = loss scalar; out[1..] = pred_perm (B,K,H,W) flat.
//
// 2-dispatch pipeline (no memsets, no extra launches):
//   cost_kernel    : 512 blocks; REGISTER-ACCUMULATOR streaming (no LDS staging,
//                    no barriers in the hot loop). Lane loads 8 pred + 8 aug
//                    float4s per pixel-quad (fully coalesced, stride-HW), logs
//                    pred once, accumulates all 64 cross terms + 8 ent terms in
//                    VGPRs. Epilogue: 63-shuffle reduce-scatter (lane l ends with
//                    wave-total of acc[bitrev6(l)]) + 10-op ent reduce + LDS
//                    combine of the 4 waves. Replaces the LDS-staged version that
//                    plateaued at ~38 us (1.76 TB/s = latency-bound staging).
//   permute_kernel : 512 blocks (full row each): fused Held-Karp DP (redundant per
//                    block, parallel) + permuted copy with aligned float4 stores;
//                    one block per batch atomicAdds the batch loss into out[0].

#define BB 64
#define KK 8
#define HW 16384
#define SPANS 8      // cost blocks per batch
#define SPAN 2048    // floats per span per row (2 quads per thread)
#define EPSF 1e-15f

// ---------- compile-time mask table: all 255 nonzero 8-bit masks, level-ordered by popcount ----------
struct MaskTab {
    unsigned char masks[255];
    int off[9];
};

constexpr MaskTab make_tab() {
    MaskTab t{};
    int idx = 0;
    for (int p = 1; p <= 8; ++p) {
        t.off[p - 1] = idx;
        for (int m = 1; m < 256; ++m) {
            int c = 0;
            for (int b = 0; b < 8; ++b) c += (m >> b) & 1;
            if (c == p) t.masks[idx++] = (unsigned char)m;
        }
    }
    t.off[8] = idx;
    return t;
}

__constant__ MaskTab kTab = make_tab();

__device__ __forceinline__ float dot4(float4 t, float4 l) {
    return t.x * l.x + t.y * l.y + t.z * l.z + t.w * l.w;
}

__device__ __forceinline__ float4 log4(float4 a) {
    float4 r;
    r.x = __logf(a.x + EPSF); r.y = __logf(a.y + EPSF);
    r.z = __logf(a.z + EPSF); r.w = __logf(a.w + EPSF);
    return r;
}

// ---------- phase 1: register-accumulator cross/ent partial sums ----------
// Grid: 512 blocks (b*8+s), 256 threads. Thread t of span s covers pixel quads
// {s*512 + it*256 + t : it in 0..1}. All 16 loads per iteration are independent
// global_load_dwordx4 (coalesced across lanes); no LDS until the epilogue.
__global__ __launch_bounds__(256) void cost_kernel(const float* __restrict__ pred,
                                                   const float* __restrict__ aug,
                                                   float* __restrict__ part,   // [512][72]
                                                   float* __restrict__ out)
{
    __shared__ float red[4][72];

    const int blk  = blockIdx.x;        // b*SPANS + s
    const int b    = blk >> 3;
    const int s    = blk & 7;
    const int tid  = threadIdx.x;
    const int wave = tid >> 6;
    const int lane = tid & 63;

    if (blk == 0 && tid == 0) out[0] = 0.f;   // loss accumulator init (pre-atomics)

    const size_t base = (size_t)b * (KK * HW);

    float acc[64];
#pragma unroll
    for (int v = 0; v < 64; ++v) acc[v] = 0.f;
    float ent[8];
#pragma unroll
    for (int j = 0; j < 8; ++j) ent[j] = 0.f;

#pragma unroll
    for (int it = 0; it < 2; ++it) {
        const int e = s * SPAN + (it * 256 + tid) * 4;   // element index within a row
        const float* pp = pred + base + e;
        const float* ap = aug  + base + e;

        float4 lp[8];
#pragma unroll
        for (int i = 0; i < 8; ++i)
            lp[i] = log4(*(const float4*)(pp + (size_t)i * HW));

#pragma unroll
        for (int j = 0; j < 8; ++j) {
            const float4 a  = *(const float4*)(ap + (size_t)j * HW);
            ent[j] += dot4(a, log4(a));
#pragma unroll
            for (int i = 0; i < 8; ++i)
                acc[i * 8 + j] += dot4(a, lp[i]);
        }
    }

    // --- wave reduce-scatter over the 64 cross accumulators (63 shuffles) ---
    // After round r (d=1<<r), live count halves; lane l ends with the wave-total
    // of original acc[bitrev6(l)].
#pragma unroll
    for (int r = 0; r < 6; ++r) {
        const int d    = 1 << r;
        const int half = 32 >> r;
        const bool hi  = (lane & d) != 0;
#pragma unroll
        for (int k = 0; k < half; ++k) {
            const float send = hi ? acc[k] : acc[k + half];
            const float recv = __shfl_xor(send, d);
            acc[k] = (hi ? acc[k + half] : acc[k]) + recv;
        }
    }

    // --- ent reduce: 3-round reduce-scatter over 8 values + 3 plain butterflies ---
#pragma unroll
    for (int r = 0; r < 3; ++r) {
        const int d    = 1 << r;
        const int half = 4 >> r;
        const bool hi  = (lane & d) != 0;
#pragma unroll
        for (int k = 0; k < half; ++k) {
            const float send = hi ? ent[k] : ent[k + half];
            const float recv = __shfl_xor(send, d);
            ent[k] = (hi ? ent[k + half] : ent[k]) + recv;
        }
    }
    float ev = ent[0];
    ev += __shfl_xor(ev, 8);
    ev += __shfl_xor(ev, 16);
    ev += __shfl_xor(ev, 32);
    // lane l holds ent_total[bitrev3(l & 7)]

    // --- combine the 4 waves via LDS, store 72 partials ---
    const int vidx = ((lane & 1) << 5) | ((lane & 2) << 3) | ((lane & 4) << 1) |
                     ((lane & 8) >> 1) | ((lane & 16) >> 3) | ((lane & 32) >> 5);
    red[wave][vidx] = acc[0];
    if (lane < 8)
        red[wave][64 + (((lane & 1) << 2) | (lane & 2) | ((lane & 4) >> 2))] = ev;
    __syncthreads();

    if (tid < 72) {
        const float ssum = red[0][tid] + red[1][tid] + red[2][tid] + red[3][tid];
        part[(size_t)blk * 72 + tid] = ssum;   // part[i*8+j]=cross[i][j]; part[64+j]=ent[j]
    }
}

// ---------- phase 2: fused DP + permuted copy (512 blocks, full row each) ----------
// grid: 512 blocks of 256 threads; block p handles pair p = b*8 + jcol (one full
// 16384-float row). Each block redundantly reduces its batch's 8 span-partials and
// runs the Held-Karp DP (~parallel). Block p==b*8 atomicAdds the batch loss.
// Stores: out+1 row base is 4B-aligned; element 3 of each row is 16B-aligned ->
// middle 4095 quads as aligned float4; head 3 + tail 1 scalar by one thread.
__global__ __launch_bounds__(256) void permute_kernel(const float* __restrict__ pred,
                                                      const float* __restrict__ part,
                                                      float* __restrict__ out)
{
    __shared__ float red[72];
    __shared__ float C[64];     // C[i*8+j] = ent[j] - cross[i][j] (unscaled)
    __shared__ float dp[256];
    __shared__ int   choice[256];
    __shared__ int   inv8[8];   // col -> src row

    const int p    = blockIdx.x;   // pair = b*8 + jcol
    const int b    = p >> 3;
    const int tid  = threadIdx.x;

    // --- reduce the 8 span-partials for batch b ---
    const float* pb = part + (size_t)b * SPANS * 72;
    if (tid < 72) {
        float s = 0.f;
#pragma unroll
        for (int c = 0; c < SPANS; ++c) s += pb[c * 72 + tid];
        red[tid] = s;
    }
    if (tid == 0) dp[0] = 0.f;
    __syncthreads();
    if (tid < 64) C[tid] = red[64 + (tid & 7)] - red[tid];
    __syncthreads();

    // --- Held-Karp DP over 255 masks, level-ordered; 32 mask slots per pass ---
    const int grp = tid >> 3;
    const int j   = tid & 7;
    for (int lvl = 1; lvl <= 8; ++lvl) {
        const int start = kTab.off[lvl - 1];
        const int end   = kTab.off[lvl];
        const float* Crow = &C[(lvl - 1) * 8];
        for (int bse = start; bse < end; bse += 32) {
            const int mi = bse + grp;
            if (mi < end) {
                const int M = kTab.masks[mi];
                float v  = 1e30f;
                int   bj = 0;
                if (M & (1 << j)) {
                    v  = dp[M ^ (1 << j)] + Crow[j];
                    bj = j;
                }
#pragma unroll
                for (int d = 1; d < 8; d <<= 1) {
                    const float ov = __shfl_xor(v, d);
                    const int   oj = __shfl_xor(bj, d);
                    if (ov < v) { v = ov; bj = oj; }
                }
                if (j == 0) { dp[M] = v; choice[M] = bj; }
            }
        }
        __syncthreads();
    }

    if (tid == 0) {
        int mask = 255;
        for (int r = 7; r >= 0; --r) {
            const int jj = choice[mask];
            inv8[jj] = r;              // column jj takes pred row r
            mask ^= 1 << jj;
        }
        if ((p & 7) == 0)              // one designated block per batch
            atomicAdd(out, dp[255] * (1.0f / (16384.0f * 512.0f)));
    }
    __syncthreads();

    // --- permuted copy of the full row (16384 elements = 4096 quads) ---
    const int src_row = inv8[p & 7];   // uniform per block
    const float* src  = pred + ((size_t)(b << 3) + src_row) * HW;
    float*      drow  = out + 1 + (size_t)p * HW;

#pragma unroll
    for (int m = 0; m < 16; ++m) {
        const int f = tid + 256 * m;              // quad index in [0,4096)
        const int e = 3 + 4 * f;
        if (f < 4095) {
            float4 v;
            v.x = src[e]; v.y = src[e + 1]; v.z = src[e + 2]; v.w = src[e + 3];
            *(float4*)(drow + e) = v;             // 16B-aligned
        } else {                                  // f==4095: head 3 + tail 1
            drow[0] = src[0]; drow[1] = src[1]; drow[2] = src[2];
            drow[16383] = src[16383];
        }
    }
}

extern "C" void kernel_launch(void* const* d_in, const int* in_sizes, int n_in,
                              void* d_out, int out_size, void* d_ws, size_t ws_size,
                              hipStream_t stream) {
    const float* pred = (const float*)d_in[0];
    const float* aug  = (const float*)d_in[1];
    float* out = (float*)d_out;
    float* part = (float*)d_ws;                      // 512*72 floats

    cost_kernel<<<dim3(BB * SPANS), dim3(256), 0, stream>>>(pred, aug, part, out);
    permute_kernel<<<dim3(512), dim3(256), 0, stream>>>(pred, part, out);
}